// Round 4
// baseline (434.956 us; speedup 1.0000x reference)
//
#include <hip/hip_runtime.h>

// LIF neuron forward: x [B=16, C=64, T=16, H=64, W=64] f32, decay (1,) f32.
//   mem   = mem_old * sigmoid(decay) * (1 - spike) + x_t
//   spike = (mem > 0.5) ? 1 : 0
// out = spikes (clip to [0,1] is identity on {0,1}).
//
// Round 3 A/B vs rounds 0-2 (all ~identical):
//  - Phase-separated: 16-load read burst -> full in-register recurrence ->
//    16-store write burst. No per-step read/write interleave (DRAM bus
//    turnaround hypothesis).
//  - PLAIN loads/stores (drop nontemporal — never A/B'd; fills hit
//    6.5 TB/s with default cache behavior).
//  - Spikes overwrite the staging registers: 64 VGPR staging total.

#define T_STEPS 16
#define HW      4096            // H*W
#define BC      1024            // B*C
#define S4      1024            // HW/4 float4 columns per (b,c)

typedef float f4 __attribute__((ext_vector_type(4)));

__global__ __launch_bounds__(256) void
lif_fwd_kernel(const float* __restrict__ x,
               const float* __restrict__ decay,
               float* __restrict__ out) {
    const unsigned tid  = blockIdx.x * blockDim.x + threadIdx.x;  // [0, BC*S4)
    const unsigned bc   = tid >> 10;
    const unsigned s4   = tid & (S4 - 1);
    const unsigned base = bc * (T_STEPS * HW) + s4 * 4;           // element offset

    const float d  = decay[0];
    const float ds = 1.0f / (1.0f + expf(-d));

    // Phase 1: pure read burst — 16 coalesced dwordx4, all outstanding.
    f4 v[T_STEPS];
#pragma unroll
    for (int t = 0; t < T_STEPS; ++t) {
        v[t] = *reinterpret_cast<const f4*>(x + base + (unsigned)t * HW);
    }

    // Phase 2: in-register recurrence; spike overwrites the staging slot.
    float mx = 0.f, my = 0.f, mz = 0.f, mw = 0.f;
    float sx = 0.f, sy = 0.f, sz = 0.f, sw = 0.f;
#pragma unroll
    for (int t = 0; t < T_STEPS; ++t) {
        // Un-fused fp32 ops to mirror XLA's separate mul/mul/add rounding.
        mx = __fadd_rn(__fmul_rn(__fmul_rn(mx, ds), 1.0f - sx), v[t].x);
        my = __fadd_rn(__fmul_rn(__fmul_rn(my, ds), 1.0f - sy), v[t].y);
        mz = __fadd_rn(__fmul_rn(__fmul_rn(mz, ds), 1.0f - sz), v[t].z);
        mw = __fadd_rn(__fmul_rn(__fmul_rn(mw, ds), 1.0f - sw), v[t].w);

        sx = (mx > 0.5f) ? 1.0f : 0.0f;
        sy = (my > 0.5f) ? 1.0f : 0.0f;
        sz = (mz > 0.5f) ? 1.0f : 0.0f;
        sw = (mw > 0.5f) ? 1.0f : 0.0f;

        f4 ov; ov.x = sx; ov.y = sy; ov.z = sz; ov.w = sw;
        v[t] = ov;
    }

    // Phase 3: pure write burst — 16 coalesced dwordx4 back-to-back.
#pragma unroll
    for (int t = 0; t < T_STEPS; ++t) {
        *reinterpret_cast<f4*>(out + base + (unsigned)t * HW) = v[t];
    }
}

extern "C" void kernel_launch(void* const* d_in, const int* in_sizes, int n_in,
                              void* d_out, int out_size, void* d_ws, size_t ws_size,
                              hipStream_t stream) {
    const float* x     = (const float*)d_in[0];
    const float* decay = (const float*)d_in[1];
    float*       out   = (float*)d_out;

    const int block = 256;
    const int grid  = (BC * S4) / block;   // 4096 blocks
    lif_fwd_kernel<<<grid, block, 0, stream>>>(x, decay, out);
}